// Round 4
// baseline (547.236 us; speedup 1.0000x reference)
//
#include <hip/hip_runtime.h>
#include <math.h>

// Problem constants
#define BATCH 65536
#define XD 362
#define ZD 100

// ws layout (bytes):
//   [0,256)                : counts[3] (int), zeroed each launch
//   [256, 786688)          : idxlist[3][65536] (int)
//   [13893888, +2007040)   : repacked bf16 weights in MFMA B-fragment order
#define WS_IDX_OFF 256
#define WS_WT_OFF  13893888

// Weight offsets in bf16 elements. Fragment order: for each matrix,
// index = ((ct*NKT + kt)*64 + lane)*8 + j, where the fragment element is
// B[k = kt*32 + (lane>>4)*8 + j][n = ct*16 + (lane&15)], zero-padded to Kp,Np.
#define OFF_W1 0        // Kp=384 Np=256
#define OFF_W2 98304    // Kp=256 Np=256
#define OFF_W3 163840   // Kp=224 Np=128
#define OFF_E1 192512   // 3 x Kp=128 Np=192, stride 24576
#define OFF_E2 266240   // 3 x Kp=160 Np=256, stride 40960
#define OFF_E3 389120   // 3 x Kp=256 Np=320, stride 81920
#define OFF_E4 634880   // 3 x Kp=320 Np=384, stride 122880

typedef short short8 __attribute__((ext_vector_type(8)));
typedef float f32x4 __attribute__((ext_vector_type(4)));

__device__ __forceinline__ unsigned short f2bf(float f) {
    union { float f; unsigned u; } v; v.f = f;
    unsigned u = v.u + 0x7fffu + ((v.u >> 16) & 1u);  // RNE
    return (unsigned short)(u >> 16);
}
__device__ __forceinline__ float bf2f(unsigned u) {
    union { unsigned u; float f; } v; v.u = u << 16; return v.f;
}

// ---------------- repack: W[K][N] fp32 -> bf16 MFMA B-fragment order --------
__global__ __launch_bounds__(256) void repack_kernel(
    const float* __restrict__ W1, const float* __restrict__ W2,
    const float* __restrict__ W3, const float* __restrict__ eW1,
    const float* __restrict__ eW2, const float* __restrict__ eW3,
    const float* __restrict__ eW4, unsigned short* __restrict__ dst) {
    int m = blockIdx.y;
    const float* src; int K, N, Kp, Np; size_t off;
    if (m == 0)      { src = W1; K = 362; N = 256; Kp = 384; Np = 256; off = OFF_W1; }
    else if (m == 1) { src = W2; K = 256; N = 200; Kp = 256; Np = 256; off = OFF_W2; }
    else if (m == 2) { src = W3; K = 200; N = 100; Kp = 224; Np = 128; off = OFF_W3; }
    else if (m <= 5) { int e = m - 3;  src = eW1 + e * 15000;  K = 100; N = 150; Kp = 128; Np = 192; off = OFF_E1 + (size_t)e * 24576; }
    else if (m <= 8) { int e = m - 6;  src = eW2 + e * 37500;  K = 150; N = 250; Kp = 160; Np = 256; off = OFF_E2 + (size_t)e * 40960; }
    else if (m <= 11){ int e = m - 9;  src = eW3 + e * 75000;  K = 250; N = 300; Kp = 256; Np = 320; off = OFF_E3 + (size_t)e * 81920; }
    else             { int e = m - 12; src = eW4 + e * 108600; K = 300; N = 362; Kp = 320; Np = 384; off = OFF_E4 + (size_t)e * 122880; }
    int nkt = Kp / 32;
    int total = Kp * Np;
    for (int i = blockIdx.x * 256 + threadIdx.x; i < total; i += gridDim.x * 256) {
        int j = i & 7, lane = (i >> 3) & 63, t = i >> 9;
        int kt = t % nkt, ct = t / nkt;
        int k = kt * 32 + (lane >> 4) * 8 + j;
        int n = ct * 16 + (lane & 15);
        float v = (k < K && n < N) ? src[(size_t)k * N + n] : 0.0f;
        dst[off + i] = f2bf(v);
    }
}

// ---------------- bucket rows by expert (wave-aggregated atomics) -----------
__global__ __launch_bounds__(256) void bucket_kernel(const int* __restrict__ a,
                                                     int* __restrict__ counts,
                                                     int* __restrict__ idxlist) {
    int b = blockIdx.x * 256 + threadIdx.x;
    int lane = threadIdx.x & 63;
    int e = a[b];
    unsigned long long below = (lane == 63) ? ~0ull >> 1
                                            : ((1ull << (lane + 1)) - 1ull) >> 1;
    int pos = 0;
#pragma unroll
    for (int ee = 0; ee < 3; ++ee) {
        unsigned long long mask = __ballot(e == ee);
        if (e == ee) {
            int leader = __ffsll((long long)mask) - 1;
            int base = 0;
            if (lane == leader)
                base = atomicAdd(&counts[ee], __popcll(mask));
            base = __shfl(base, leader, 64);
            pos = base + __popcll(mask & below);
        }
    }
    idxlist[e * BATCH + pos] = b;
}

// MFMA layer over one 16-row LDS tile.
// in: bf16 LDS [16][LDI] (zero-padded to KP). out: bf16 LDS [16][LDO],
// relu(acc+bias), cols n<NSTORE written, zeros for NREAL<=n<NSTORE.
// Wave wv owns col-tiles {wv, wv+4, ...}. A-frag: [m=lane&15][k=quad*8+j];
// B-frag from pre-swizzled global; C/D: row=quad*4+reg, col=lane&15.
template <int KP, int NP, int LDI, int LDO, int NREAL, int NSTORE>
__device__ __forceinline__ void mfma_layer(
    const unsigned short* __restrict__ Wf, const float* __restrict__ bias,
    const unsigned short* __restrict__ inL, unsigned short* __restrict__ outL,
    int wv, int lane) {
    constexpr int NKT = KP / 32, NCT = NP / 16, CPW = NCT / 4;
    const int quad = lane >> 4, l15 = lane & 15;
    f32x4 acc[CPW];
#pragma unroll
    for (int i = 0; i < CPW; ++i) acc[i] = (f32x4){0.f, 0.f, 0.f, 0.f};
    const unsigned short* ap = inL + l15 * LDI + quad * 8;
#pragma unroll
    for (int kt = 0; kt < NKT; ++kt) {
        short8 a = *(const short8*)(ap + kt * 32);
        short8 bf[CPW];
#pragma unroll
        for (int i = 0; i < CPW; ++i)
            bf[i] = *(const short8*)(Wf + ((size_t)((wv + 4 * i) * NKT + kt) * 64 + lane) * 8);
#pragma unroll
        for (int i = 0; i < CPW; ++i)
            acc[i] = __builtin_amdgcn_mfma_f32_16x16x32_bf16(a, bf[i], acc[i], 0, 0, 0);
    }
#pragma unroll
    for (int i = 0; i < CPW; ++i) {
        int n = (wv + 4 * i) * 16 + l15;
        if (n < NSTORE) {
            float bv = (n < NREAL) ? bias[n] : 0.f;
#pragma unroll
            for (int r = 0; r < 4; ++r) {
                int row = quad * 4 + r;
                float v = fmaxf(acc[i][r] + bv, 0.f);
                outL[row * LDO + n] = (n < NREAL) ? f2bf(v) : (unsigned short)0;
            }
        }
    }
}

// ------- fused encoder + expert chain + loss over bucketed rows, 16/block ---
// Overlaid ping-pong LDS: B0 (16x392) = x -> h2 -> eh1 -> eh3,
//                         B1 (16x328) = h1 -> z -> eh2.
// delta (xn-x) lives in per-lane registers (bf16-packed), loaded just before
// E3 so the loads are in flight under E3/E4 compute.
__global__ __launch_bounds__(256, 6) void fused_kernel(
    const float* __restrict__ x, const float* __restrict__ xn,
    const int* __restrict__ counts, const int* __restrict__ idxlist,
    const unsigned short* __restrict__ Wts,
    const float* __restrict__ b1, const float* __restrict__ b2,
    const float* __restrict__ b3, const float* __restrict__ eb1,
    const float* __restrict__ eb2, const float* __restrict__ eb3,
    const float* __restrict__ eb4, float* __restrict__ out) {
    int e = blockIdx.y;
    int cnt = counts[e];
    int start = blockIdx.x * 16;
    if (start >= cnt) return;
    int nrows = min(16, cnt - start);

    __shared__ unsigned short B0[16 * 392];
    __shared__ unsigned short B1[16 * 328];
    __shared__ int s_idx[16];
    __shared__ float s_part[4];

    int tid = threadIdx.x;
    int wv = tid >> 6, lane = tid & 63;
    const int quad = lane >> 4, l15 = lane & 15;

    if (tid < 16)
        s_idx[tid] = (tid < nrows) ? idxlist[e * BATCH + start + tid] : -1;
    __syncthreads();

    // stage gathered x rows -> B0 bf16 ld392 (196 dwords/row), zero pad k>=362
    {
        unsigned* dP = (unsigned*)B0;
        for (int i = tid; i < 16 * 196; i += 256) {
            int r = i / 196, c = i - r * 196;
            int b = s_idx[r];
            unsigned pk = 0u;
            if (c < 181 && b >= 0) {
                float2 v = *(const float2*)(x + (size_t)b * 362 + 2 * c);
                pk = (unsigned)f2bf(v.x) | ((unsigned)f2bf(v.y) << 16);
            }
            dP[i] = pk;
        }
    }
    __syncthreads();
    // enc L1: x(Kp384, B0 ld392) -> h1 (B1 ld264)
    mfma_layer<384, 256, 392, 264, 256, 256>(Wts + OFF_W1, b1, B0, B1, wv, lane);
    __syncthreads();
    // enc L2: h1(Kp256, B1 ld264) -> h2 (B0 ld264, 200 real pad 224)
    mfma_layer<256, 256, 264, 264, 200, 224>(Wts + OFF_W2, b2, B1, B0, wv, lane);
    __syncthreads();
    // enc L3: h2(Kp224, B0 ld264) -> z (B1 ld136, 100 real sigmoid, pad 128)
    {
        const unsigned short* W3f = Wts + OFF_W3;
        f32x4 acc3[2];
#pragma unroll
        for (int i = 0; i < 2; ++i) acc3[i] = (f32x4){0.f, 0.f, 0.f, 0.f};
        const unsigned short* ap = B0 + l15 * 264 + quad * 8;
#pragma unroll
        for (int kt = 0; kt < 7; ++kt) {
            short8 a = *(const short8*)(ap + kt * 32);
            short8 bf[2];
#pragma unroll
            for (int i = 0; i < 2; ++i)
                bf[i] = *(const short8*)(W3f + ((size_t)((wv + 4 * i) * 7 + kt) * 64 + lane) * 8);
#pragma unroll
            for (int i = 0; i < 2; ++i)
                acc3[i] = __builtin_amdgcn_mfma_f32_16x16x32_bf16(a, bf[i], acc3[i], 0, 0, 0);
        }
#pragma unroll
        for (int i = 0; i < 2; ++i) {
            int n = (wv + 4 * i) * 16 + l15;  // covers 0..127
            float bv = (n < 100) ? b3[n] : 0.f;
#pragma unroll
            for (int r = 0; r < 4; ++r) {
                int row = quad * 4 + r;
                float s = 1.0f / (1.0f + expf(-(acc3[i][r] + bv)));
                B1[row * 136 + n] = (n < 100) ? f2bf(s) : (unsigned short)0;
            }
        }
    }
    __syncthreads();
    // expert chain
    // E1: z(Kp128, B1 ld136) -> eh1 (B0 ld168, 150 real pad 160)
    mfma_layer<128, 192, 136, 168, 150, 160>(Wts + OFF_E1 + (size_t)e * 24576,
                                             eb1 + e * 150, B1, B0, wv, lane);
    __syncthreads();
    // E2: eh1(Kp160, B0 ld168) -> eh2 (B1 ld264, 250 real pad 256)
    mfma_layer<160, 256, 168, 264, 250, 256>(Wts + OFF_E2 + (size_t)e * 40960,
                                             eb2 + e * 250, B0, B1, wv, lane);
    __syncthreads();

    // delta prefetch into registers (bf16-packed): lane owns
    // (row=quad*4+r, n=(wv+4i)*16+l15). Loads overlap E3's compute window.
    unsigned dpk[6][2];
#pragma unroll
    for (int i = 0; i < 6; ++i) {
        int n = (wv + 4 * i) * 16 + l15;
        float d[4];
#pragma unroll
        for (int r = 0; r < 4; ++r) {
            int b = s_idx[quad * 4 + r];
            d[r] = (n < 362 && b >= 0)
                     ? (xn[(size_t)b * 362 + n] - x[(size_t)b * 362 + n]) : 0.f;
        }
        dpk[i][0] = (unsigned)f2bf(d[0]) | ((unsigned)f2bf(d[1]) << 16);
        dpk[i][1] = (unsigned)f2bf(d[2]) | ((unsigned)f2bf(d[3]) << 16);
    }

    // E3: eh2(Kp256, B1 ld264) -> eh3 (B0 ld328, 300 real pad 320)
    mfma_layer<256, 320, 264, 328, 300, 320>(Wts + OFF_E3 + (size_t)e * 81920,
                                             eb3 + e * 300, B1, B0, wv, lane);
    __syncthreads();

    // E4: eh3(Kp320, B0 ld328), Np=384 (CPW=6), fused loss vs delta regs
    float lacc = 0.0f;
    {
        constexpr int NKT = 10, CPW = 6;
        const unsigned short* Wf = Wts + OFF_E4 + (size_t)e * 122880;
        const float* bias4 = eb4 + (size_t)e * 362;
        f32x4 acc[CPW];
#pragma unroll
        for (int i = 0; i < CPW; ++i) acc[i] = (f32x4){0.f, 0.f, 0.f, 0.f};
        const unsigned short* ap = B0 + l15 * 328 + quad * 8;
#pragma unroll
        for (int kt = 0; kt < NKT; ++kt) {
            short8 a = *(const short8*)(ap + kt * 32);
            short8 bf[CPW];
#pragma unroll
            for (int i = 0; i < CPW; ++i)
                bf[i] = *(const short8*)(Wf + ((size_t)((wv + 4 * i) * NKT + kt) * 64 + lane) * 8);
#pragma unroll
            for (int i = 0; i < CPW; ++i)
                acc[i] = __builtin_amdgcn_mfma_f32_16x16x32_bf16(a, bf[i], acc[i], 0, 0, 0);
        }
        const float WC0 = 1.0f / 65536.0f;
        const float WCR = 1.0f / (361.0f * 65536.0f);
#pragma unroll
        for (int i = 0; i < CPW; ++i) {
            int n = (wv + 4 * i) * 16 + l15;
            if (n < 362) {
                float bv = bias4[n];
                float wgt = (n == 0) ? WC0 : WCR;
#pragma unroll
                for (int r = 0; r < 4; ++r) {
                    int b = s_idx[quad * 4 + r];
                    if (b >= 0) {
                        float pred = acc[i][r] + bv;
                        unsigned pr = dpk[i][r >> 1];
                        float delta = bf2f((r & 1) ? (pr >> 16) : (pr & 0xffffu));
                        float err = pred - delta;
                        lacc += wgt * err * err;
                    }
                }
            }
        }
    }
    // block reduction -> atomicAdd
    for (int off = 32; off; off >>= 1)
        lacc += __shfl_down(lacc, off, 64);
    if ((tid & 63) == 0) s_part[wv] = lacc;
    __syncthreads();
    if (tid == 0)
        atomicAdd(out, s_part[0] + s_part[1] + s_part[2] + s_part[3]);
}

extern "C" void kernel_launch(void* const* d_in, const int* in_sizes, int n_in,
                              void* d_out, int out_size, void* d_ws, size_t ws_size,
                              hipStream_t stream) {
    const float* x   = (const float*)d_in[0];
    const float* xn  = (const float*)d_in[1];
    const int*   a   = (const int*)d_in[2];
    const float* W1  = (const float*)d_in[3];
    const float* b1  = (const float*)d_in[4];
    const float* W2  = (const float*)d_in[5];
    const float* b2  = (const float*)d_in[6];
    const float* W3  = (const float*)d_in[7];
    const float* b3  = (const float*)d_in[8];
    const float* eW1 = (const float*)d_in[9];
    const float* eb1 = (const float*)d_in[10];
    const float* eW2 = (const float*)d_in[11];
    const float* eb2 = (const float*)d_in[12];
    const float* eW3 = (const float*)d_in[13];
    const float* eb3 = (const float*)d_in[14];
    const float* eW4 = (const float*)d_in[15];
    const float* eb4 = (const float*)d_in[16];

    char* ws = (char*)d_ws;
    int* counts           = (int*)ws;
    int* idxlist          = (int*)(ws + WS_IDX_OFF);
    unsigned short* Wts   = (unsigned short*)(ws + WS_WT_OFF);

    hipMemsetAsync(counts, 0, 256, stream);
    hipMemsetAsync(d_out, 0, sizeof(float), stream);

    repack_kernel<<<dim3(32, 15), 256, 0, stream>>>(W1, W2, W3, eW1, eW2, eW3, eW4, Wts);
    bucket_kernel<<<BATCH / 256, 256, 0, stream>>>(a, counts, idxlist);
    fused_kernel<<<dim3(BATCH / 16, 3), 256, 0, stream>>>(
        x, xn, counts, idxlist, Wts, b1, b2, b3, eb1, eb2, eb3, eb4, (float*)d_out);
}

// Round 5
// 458.004 us; speedup vs baseline: 1.1948x; 1.1948x over previous
//
#include <hip/hip_runtime.h>
#include <math.h>

// Problem constants
#define BATCH 65536
#define XD 362
#define ZD 100

// ws layout (bytes):
//   [0,256)                : counts[3] (int), zeroed each launch
//   [256, 786688)          : idxlist[3][65536] (int)
//   [13893888, +2007040)   : repacked bf16 weights in MFMA B-fragment order
#define WS_IDX_OFF 256
#define WS_WT_OFF  13893888

// Weight offsets in bf16 elements. Fragment order: for each matrix,
// index = ((ct*NKT + kt)*64 + lane)*8 + j, where the fragment element is
// B[k = kt*32 + (lane>>4)*8 + j][n = ct*16 + (lane&15)], zero-padded to Kp,Np.
#define OFF_W1 0        // Kp=384 Np=256
#define OFF_W2 98304    // Kp=256 Np=256
#define OFF_W3 163840   // Kp=224 Np=128
#define OFF_E1 192512   // 3 x Kp=128 Np=192, stride 24576
#define OFF_E2 266240   // 3 x Kp=160 Np=256, stride 40960
#define OFF_E3 389120   // 3 x Kp=256 Np=320, stride 81920
#define OFF_E4 634880   // 3 x Kp=320 Np=384, stride 122880

typedef short short8 __attribute__((ext_vector_type(8)));
typedef float f32x4 __attribute__((ext_vector_type(4)));

__device__ __forceinline__ unsigned short f2bf(float f) {
    union { float f; unsigned u; } v; v.f = f;
    unsigned u = v.u + 0x7fffu + ((v.u >> 16) & 1u);  // RNE
    return (unsigned short)(u >> 16);
}
__device__ __forceinline__ float bf2f(unsigned u) {
    union { unsigned u; float f; } v; v.u = u << 16; return v.f;
}

// ---------------- repack: W[K][N] fp32 -> bf16 MFMA B-fragment order --------
__global__ __launch_bounds__(256) void repack_kernel(
    const float* __restrict__ W1, const float* __restrict__ W2,
    const float* __restrict__ W3, const float* __restrict__ eW1,
    const float* __restrict__ eW2, const float* __restrict__ eW3,
    const float* __restrict__ eW4, unsigned short* __restrict__ dst) {
    int m = blockIdx.y;
    const float* src; int K, N, Kp, Np; size_t off;
    if (m == 0)      { src = W1; K = 362; N = 256; Kp = 384; Np = 256; off = OFF_W1; }
    else if (m == 1) { src = W2; K = 256; N = 200; Kp = 256; Np = 256; off = OFF_W2; }
    else if (m == 2) { src = W3; K = 200; N = 100; Kp = 224; Np = 128; off = OFF_W3; }
    else if (m <= 5) { int e = m - 3;  src = eW1 + e * 15000;  K = 100; N = 150; Kp = 128; Np = 192; off = OFF_E1 + (size_t)e * 24576; }
    else if (m <= 8) { int e = m - 6;  src = eW2 + e * 37500;  K = 150; N = 250; Kp = 160; Np = 256; off = OFF_E2 + (size_t)e * 40960; }
    else if (m <= 11){ int e = m - 9;  src = eW3 + e * 75000;  K = 250; N = 300; Kp = 256; Np = 320; off = OFF_E3 + (size_t)e * 81920; }
    else             { int e = m - 12; src = eW4 + e * 108600; K = 300; N = 362; Kp = 320; Np = 384; off = OFF_E4 + (size_t)e * 122880; }
    int nkt = Kp / 32;
    int total = Kp * Np;
    for (int i = blockIdx.x * 256 + threadIdx.x; i < total; i += gridDim.x * 256) {
        int j = i & 7, lane = (i >> 3) & 63, t = i >> 9;
        int kt = t % nkt, ct = t / nkt;
        int k = kt * 32 + (lane >> 4) * 8 + j;
        int n = ct * 16 + (lane & 15);
        float v = (k < K && n < N) ? src[(size_t)k * N + n] : 0.0f;
        dst[off + i] = f2bf(v);
    }
}

// ---------------- bucket rows by expert (wave-aggregated atomics) -----------
__global__ __launch_bounds__(256) void bucket_kernel(const int* __restrict__ a,
                                                     int* __restrict__ counts,
                                                     int* __restrict__ idxlist) {
    int b = blockIdx.x * 256 + threadIdx.x;
    int lane = threadIdx.x & 63;
    int e = a[b];
    unsigned long long below = (lane == 63) ? ~0ull >> 1
                                            : ((1ull << (lane + 1)) - 1ull) >> 1;
    int pos = 0;
#pragma unroll
    for (int ee = 0; ee < 3; ++ee) {
        unsigned long long mask = __ballot(e == ee);
        if (e == ee) {
            int leader = __ffsll((long long)mask) - 1;
            int base = 0;
            if (lane == leader)
                base = atomicAdd(&counts[ee], __popcll(mask));
            base = __shfl(base, leader, 64);
            pos = base + __popcll(mask & below);
        }
    }
    idxlist[e * BATCH + pos] = b;
}

// Register-only prefetch of the first PF kt-groups of a phase's B-fragments.
// Issued BEFORE the barrier preceding the phase: loads are in flight during
// the barrier's vmcnt drain, so the phase starts with data in registers.
template <int NKT, int CPW, int PF>
__device__ __forceinline__ void prefetch_b(const unsigned short* __restrict__ Wf,
                                           int wv, int lane, short8* pf) {
#pragma unroll
    for (int p = 0; p < PF; ++p)
#pragma unroll
        for (int i = 0; i < CPW; ++i)
            pf[p * CPW + i] =
                *(const short8*)(Wf + ((size_t)((wv + 4 * i) * NKT + p) * 64 + lane) * 8);
}

// MFMA layer over one 16-row LDS tile.
// in: bf16 LDS [16][LDI] (zero-padded to KP). out: bf16 LDS [16][LDO],
// relu(acc+bias), cols n<NSTORE written, zeros for NREAL<=n<NSTORE.
// Wave wv owns col-tiles {wv, wv+4, ...}. First PF kt-groups of B come from
// the prefetch registers pf. A-frag: [m=lane&15][k=quad*8+j]; C/D:
// row=quad*4+reg, col=lane&15.
template <int KP, int NP, int LDI, int LDO, int NREAL, int NSTORE, int PF>
__device__ __forceinline__ void mfma_layer(
    const unsigned short* __restrict__ Wf, const float* __restrict__ bias,
    const unsigned short* __restrict__ inL, unsigned short* __restrict__ outL,
    int wv, int lane, const short8* __restrict__ pf) {
    constexpr int NKT = KP / 32, NCT = NP / 16, CPW = NCT / 4;
    const int quad = lane >> 4, l15 = lane & 15;
    f32x4 acc[CPW];
#pragma unroll
    for (int i = 0; i < CPW; ++i) acc[i] = (f32x4){0.f, 0.f, 0.f, 0.f};
    const unsigned short* ap = inL + l15 * LDI + quad * 8;
#pragma unroll
    for (int kt = 0; kt < NKT; ++kt) {
        short8 a = *(const short8*)(ap + kt * 32);
        short8 bf[CPW];
#pragma unroll
        for (int i = 0; i < CPW; ++i)
            bf[i] = (kt < PF)
                ? pf[kt * CPW + i]
                : *(const short8*)(Wf + ((size_t)((wv + 4 * i) * NKT + kt) * 64 + lane) * 8);
#pragma unroll
        for (int i = 0; i < CPW; ++i)
            acc[i] = __builtin_amdgcn_mfma_f32_16x16x32_bf16(a, bf[i], acc[i], 0, 0, 0);
    }
#pragma unroll
    for (int i = 0; i < CPW; ++i) {
        int n = (wv + 4 * i) * 16 + l15;
        if (n < NSTORE) {
            float bv = (n < NREAL) ? bias[n] : 0.f;
#pragma unroll
            for (int r = 0; r < 4; ++r) {
                int row = quad * 4 + r;
                float v = fmaxf(acc[i][r] + bv, 0.f);
                outL[row * LDO + n] = (n < NREAL) ? f2bf(v) : (unsigned short)0;
            }
        }
    }
}

// ------- fused encoder + expert chain + loss over bucketed rows, 16/block ---
// P (16x392): x bf16 -> delta bf16 (in-place RMW between L1 and L2)
// Q (16x264): h1 -> z -> eh2 ; R (16x328): h2 -> eh1 -> eh3
// Cross-barrier register prefetch of each phase's first B-fragments.
__global__ __launch_bounds__(256, 5) void fused_kernel(
    const float* __restrict__ x, const float* __restrict__ xn,
    const int* __restrict__ counts, const int* __restrict__ idxlist,
    const unsigned short* __restrict__ Wts,
    const float* __restrict__ b1, const float* __restrict__ b2,
    const float* __restrict__ b3, const float* __restrict__ eb1,
    const float* __restrict__ eb2, const float* __restrict__ eb3,
    const float* __restrict__ eb4, float* __restrict__ out) {
    int e = blockIdx.y;
    int cnt = counts[e];
    int start = blockIdx.x * 16;
    if (start >= cnt) return;
    int nrows = min(16, cnt - start);

    __shared__ unsigned short P[16 * 392];
    __shared__ unsigned short Q[16 * 264];
    __shared__ unsigned short R[16 * 328];
    __shared__ int s_idx[16];
    __shared__ float s_part[4];

    int tid = threadIdx.x;
    int wv = tid >> 6, lane = tid & 63;
    const int quad = lane >> 4, l15 = lane & 15;

    short8 pfb[10];  // prefetch registers, transient per phase

    if (tid < 16)
        s_idx[tid] = (tid < nrows) ? idxlist[e * BATCH + start + tid] : -1;

    // prefetch L1 kt=0,1 while x staging runs
    prefetch_b<12, 4, 2>(Wts + OFF_W1, wv, lane, pfb);
    __syncthreads();

    // stage gathered x rows -> P bf16 ld392 (196 dwords/row), zero pad k>=362
    {
        unsigned* dP = (unsigned*)P;
        for (int i = tid; i < 16 * 196; i += 256) {
            int r = i / 196, c = i - r * 196;
            int b = s_idx[r];
            unsigned pk = 0u;
            if (c < 181 && b >= 0) {
                float2 v = *(const float2*)(x + (size_t)b * 362 + 2 * c);
                pk = (unsigned)f2bf(v.x) | ((unsigned)f2bf(v.y) << 16);
            }
            dP[i] = pk;
        }
    }
    __syncthreads();
    // enc L1: x(Kp384, P ld392) -> h1 (Q ld264)
    mfma_layer<384, 256, 392, 264, 256, 256, 2>(Wts + OFF_W1, b1, P, Q, wv, lane, pfb);
    prefetch_b<8, 4, 2>(Wts + OFF_W2, wv, lane, pfb);
    __syncthreads();
    // delta staging: read xn coalesced, delta = xn - x(bf16 in P), overwrite P.
    {
        unsigned* dP = (unsigned*)P;
        for (int i = tid; i < 16 * 196; i += 256) {
            int r = i / 196, c = i - r * 196;
            int b = s_idx[r];
            unsigned pk = 0u;
            if (c < 181 && b >= 0) {
                float2 v = *(const float2*)(xn + (size_t)b * 362 + 2 * c);
                unsigned xp = dP[i];
                float x0 = bf2f(xp & 0xffffu), x1 = bf2f(xp >> 16);
                pk = (unsigned)f2bf(v.x - x0) | ((unsigned)f2bf(v.y - x1) << 16);
            }
            dP[i] = pk;
        }
    }
    // enc L2: h1(Kp256, Q ld264) -> h2 (R ld264 region, 200 real pad 224)
    mfma_layer<256, 256, 264, 264, 200, 224, 2>(Wts + OFF_W2, b2, Q, R, wv, lane, pfb);
    prefetch_b<7, 2, 2>(Wts + OFF_W3, wv, lane, pfb);
    __syncthreads();
    // enc L3: h2(Kp224, R ld264) -> z (Q ld136, 100 real sigmoid, pad 128)
    {
        const unsigned short* W3f = Wts + OFF_W3;
        f32x4 acc3[2];
#pragma unroll
        for (int i = 0; i < 2; ++i) acc3[i] = (f32x4){0.f, 0.f, 0.f, 0.f};
        const unsigned short* ap = R + l15 * 264 + quad * 8;
#pragma unroll
        for (int kt = 0; kt < 7; ++kt) {
            short8 a = *(const short8*)(ap + kt * 32);
            short8 bf[2];
#pragma unroll
            for (int i = 0; i < 2; ++i)
                bf[i] = (kt < 2) ? pfb[kt * 2 + i]
                    : *(const short8*)(W3f + ((size_t)((wv + 4 * i) * 7 + kt) * 64 + lane) * 8);
#pragma unroll
            for (int i = 0; i < 2; ++i)
                acc3[i] = __builtin_amdgcn_mfma_f32_16x16x32_bf16(a, bf[i], acc3[i], 0, 0, 0);
        }
#pragma unroll
        for (int i = 0; i < 2; ++i) {
            int n = (wv + 4 * i) * 16 + l15;  // covers 0..127
            float bv = (n < 100) ? b3[n] : 0.f;
#pragma unroll
            for (int r = 0; r < 4; ++r) {
                int row = quad * 4 + r;
                float s = 1.0f / (1.0f + expf(-(acc3[i][r] + bv)));
                Q[row * 136 + n] = (n < 100) ? f2bf(s) : (unsigned short)0;
            }
        }
    }
    prefetch_b<4, 3, 2>(Wts + OFF_E1 + (size_t)e * 24576, wv, lane, pfb);
    __syncthreads();
    // E1: z(Kp128, Q ld136) -> eh1 (R ld168, 150 real pad 160)
    mfma_layer<128, 192, 136, 168, 150, 160, 2>(Wts + OFF_E1 + (size_t)e * 24576,
                                                eb1 + e * 150, Q, R, wv, lane, pfb);
    prefetch_b<5, 4, 2>(Wts + OFF_E2 + (size_t)e * 40960, wv, lane, pfb);
    __syncthreads();
    // E2: eh1(Kp160, R ld168) -> eh2 (Q ld264, 250 real pad 256)
    mfma_layer<160, 256, 168, 264, 250, 256, 2>(Wts + OFF_E2 + (size_t)e * 40960,
                                                eb2 + e * 250, R, Q, wv, lane, pfb);
    prefetch_b<8, 5, 2>(Wts + OFF_E3 + (size_t)e * 81920, wv, lane, pfb);
    __syncthreads();
    // E3: eh2(Kp256, Q ld264) -> eh3 (R ld328, 300 real pad 320)
    mfma_layer<256, 320, 264, 328, 300, 320, 2>(Wts + OFF_E3 + (size_t)e * 81920,
                                                eb3 + e * 300, Q, R, wv, lane, pfb);
    prefetch_b<10, 6, 1>(Wts + OFF_E4 + (size_t)e * 122880, wv, lane, pfb);
    __syncthreads();

    // E4: eh3(Kp320, R ld328), Np=384 (CPW=6), fused loss vs delta (in P)
    float lacc = 0.0f;
    {
        constexpr int NKT = 10, CPW = 6;
        const unsigned short* Wf = Wts + OFF_E4 + (size_t)e * 122880;
        const float* bias4 = eb4 + (size_t)e * 362;
        f32x4 acc[CPW];
#pragma unroll
        for (int i = 0; i < CPW; ++i) acc[i] = (f32x4){0.f, 0.f, 0.f, 0.f};
        const unsigned short* ap = R + l15 * 328 + quad * 8;
#pragma unroll
        for (int kt = 0; kt < NKT; ++kt) {
            short8 a = *(const short8*)(ap + kt * 32);
            short8 bf[CPW];
#pragma unroll
            for (int i = 0; i < CPW; ++i)
                bf[i] = (kt < 1) ? pfb[i]
                    : *(const short8*)(Wf + ((size_t)((wv + 4 * i) * NKT + kt) * 64 + lane) * 8);
#pragma unroll
            for (int i = 0; i < CPW; ++i)
                acc[i] = __builtin_amdgcn_mfma_f32_16x16x32_bf16(a, bf[i], acc[i], 0, 0, 0);
        }
        const float WC0 = 1.0f / 65536.0f;
        const float WCR = 1.0f / (361.0f * 65536.0f);
#pragma unroll
        for (int i = 0; i < CPW; ++i) {
            int n = (wv + 4 * i) * 16 + l15;
            if (n < 362) {
                float bv = bias4[n];
                float wgt = (n == 0) ? WC0 : WCR;
#pragma unroll
                for (int r = 0; r < 4; ++r) {
                    int row = quad * 4 + r;
                    int b = s_idx[row];
                    if (b >= 0) {
                        float pred = acc[i][r] + bv;
                        float delta = bf2f((unsigned)P[row * 392 + n]);
                        float err = pred - delta;
                        lacc += wgt * err * err;
                    }
                }
            }
        }
    }
    // block reduction -> atomicAdd
    for (int off = 32; off; off >>= 1)
        lacc += __shfl_down(lacc, off, 64);
    if ((tid & 63) == 0) s_part[wv] = lacc;
    __syncthreads();
    if (tid == 0)
        atomicAdd(out, s_part[0] + s_part[1] + s_part[2] + s_part[3]);
}

extern "C" void kernel_launch(void* const* d_in, const int* in_sizes, int n_in,
                              void* d_out, int out_size, void* d_ws, size_t ws_size,
                              hipStream_t stream) {
    const float* x   = (const float*)d_in[0];
    const float* xn  = (const float*)d_in[1];
    const int*   a   = (const int*)d_in[2];
    const float* W1  = (const float*)d_in[3];
    const float* b1  = (const float*)d_in[4];
    const float* W2  = (const float*)d_in[5];
    const float* b2  = (const float*)d_in[6];
    const float* W3  = (const float*)d_in[7];
    const float* b3  = (const float*)d_in[8];
    const float* eW1 = (const float*)d_in[9];
    const float* eb1 = (const float*)d_in[10];
    const float* eW2 = (const float*)d_in[11];
    const float* eb2 = (const float*)d_in[12];
    const float* eW3 = (const float*)d_in[13];
    const float* eb3 = (const float*)d_in[14];
    const float* eW4 = (const float*)d_in[15];
    const float* eb4 = (const float*)d_in[16];

    char* ws = (char*)d_ws;
    int* counts           = (int*)ws;
    int* idxlist          = (int*)(ws + WS_IDX_OFF);
    unsigned short* Wts   = (unsigned short*)(ws + WS_WT_OFF);

    hipMemsetAsync(counts, 0, 256, stream);
    hipMemsetAsync(d_out, 0, sizeof(float), stream);

    repack_kernel<<<dim3(32, 15), 256, 0, stream>>>(W1, W2, W3, eW1, eW2, eW3, eW4, Wts);
    bucket_kernel<<<BATCH / 256, 256, 0, stream>>>(a, counts, idxlist);
    fused_kernel<<<dim3(BATCH / 16, 3), 256, 0, stream>>>(
        x, xn, counts, idxlist, Wts, b1, b2, b3, eb1, eb2, eb3, eb4, (float*)d_out);
}

// Round 6
// 423.457 us; speedup vs baseline: 1.2923x; 1.0816x over previous
//
#include <hip/hip_runtime.h>
#include <math.h>

// Problem constants
#define BATCH 65536
#define XD 362
#define ZD 100

// ws layout (bytes):
//   [0,256)               : counts[3] (int), zeroed each launch
//   [256, 786688)         : idxlist[3][65536] (int)
//   [786688, +4308992)    : repacked bf16 weights in MFMA B-fragment order
#define WS_IDX_OFF 256
#define WS_WT_OFF  786688

// Weight offsets in bf16 elements. Fragment order: for each matrix,
// index = ((ct*NKT + kt)*64 + lane)*8 + j, where the fragment element is
// B[k = kt*32 + (lane>>4)*8 + j][n = ct*16 + (lane&15)], zero-padded to Kp,Np.
// Np padded to multiples of 128 for the 8-way column split.
#define OFF_W1 0        // Kp=384 Np=256 (98304)
#define OFF_W2 98304    // Kp=256 Np=256 (65536)
#define OFF_W3 163840   // Kp=224 Np=128 (28672)
#define OFF_E1 192512   // 3 x Kp=128 Np=256, stride 32768
#define OFF_E2 290816   // 3 x Kp=160 Np=256, stride 40960
#define OFF_E3 413696   // 3 x Kp=256 Np=384, stride 98304
#define OFF_E4 708608   // 3 x Kp=320 Np=384, stride 122880

typedef short short8 __attribute__((ext_vector_type(8)));
typedef float f32x4 __attribute__((ext_vector_type(4)));

__device__ __forceinline__ unsigned short f2bf(float f) {
    union { float f; unsigned u; } v; v.f = f;
    unsigned u = v.u + 0x7fffu + ((v.u >> 16) & 1u);  // RNE
    return (unsigned short)(u >> 16);
}
__device__ __forceinline__ float bf2f(unsigned u) {
    union { unsigned u; float f; } v; v.u = u << 16; return v.f;
}

// ---------------- repack: W[K][N] fp32 -> bf16 MFMA B-fragment order --------
__global__ __launch_bounds__(256) void repack_kernel(
    const float* __restrict__ W1, const float* __restrict__ W2,
    const float* __restrict__ W3, const float* __restrict__ eW1,
    const float* __restrict__ eW2, const float* __restrict__ eW3,
    const float* __restrict__ eW4, unsigned short* __restrict__ dst) {
    int m = blockIdx.y;
    const float* src; int K, N, Kp, Np; size_t off;
    if (m == 0)      { src = W1; K = 362; N = 256; Kp = 384; Np = 256; off = OFF_W1; }
    else if (m == 1) { src = W2; K = 256; N = 200; Kp = 256; Np = 256; off = OFF_W2; }
    else if (m == 2) { src = W3; K = 200; N = 100; Kp = 224; Np = 128; off = OFF_W3; }
    else if (m <= 5) { int e = m - 3;  src = eW1 + e * 15000;  K = 100; N = 150; Kp = 128; Np = 256; off = OFF_E1 + (size_t)e * 32768; }
    else if (m <= 8) { int e = m - 6;  src = eW2 + e * 37500;  K = 150; N = 250; Kp = 160; Np = 256; off = OFF_E2 + (size_t)e * 40960; }
    else if (m <= 11){ int e = m - 9;  src = eW3 + e * 75000;  K = 250; N = 300; Kp = 256; Np = 384; off = OFF_E3 + (size_t)e * 98304; }
    else             { int e = m - 12; src = eW4 + e * 108600; K = 300; N = 362; Kp = 320; Np = 384; off = OFF_E4 + (size_t)e * 122880; }
    int nkt = Kp / 32;
    int total = Kp * Np;
    for (int i = blockIdx.x * 256 + threadIdx.x; i < total; i += gridDim.x * 256) {
        int j = i & 7, lane = (i >> 3) & 63, t = i >> 9;
        int kt = t % nkt, ct = t / nkt;
        int k = kt * 32 + (lane >> 4) * 8 + j;
        int n = ct * 16 + (lane & 15);
        float v = (k < K && n < N) ? src[(size_t)k * N + n] : 0.0f;
        dst[off + i] = f2bf(v);
    }
}

// ---------------- bucket rows by expert (wave-aggregated atomics) -----------
__global__ __launch_bounds__(256) void bucket_kernel(const int* __restrict__ a,
                                                     int* __restrict__ counts,
                                                     int* __restrict__ idxlist) {
    int b = blockIdx.x * 256 + threadIdx.x;
    int lane = threadIdx.x & 63;
    int e = a[b];
    unsigned long long below = (lane == 63) ? ~0ull >> 1
                                            : ((1ull << (lane + 1)) - 1ull) >> 1;
    int pos = 0;
#pragma unroll
    for (int ee = 0; ee < 3; ++ee) {
        unsigned long long mask = __ballot(e == ee);
        if (e == ee) {
            int leader = __ffsll((long long)mask) - 1;
            int base = 0;
            if (lane == leader)
                base = atomicAdd(&counts[ee], __popcll(mask));
            base = __shfl(base, leader, 64);
            pos = base + __popcll(mask & below);
        }
    }
    idxlist[e * BATCH + pos] = b;
}

// MFMA layer over a 32-row LDS tile, 8-wave column split, RT=2 row-tiles.
// in: bf16 LDS [32][LDI] (zero-padded to KP). out: bf16 LDS [32][LDO],
// relu(acc+bias), cols n<NSTORE written, zeros for NREAL<=n<NSTORE.
// Wave wv owns col-tiles {wv, wv+8, ...}; each B-fragment feeds 2 MFMAs
// (row-tiles 0,1) -> halves per-row L2 weight traffic vs 16-row blocks.
// A-frag: [m=lane&15][k=quad*8+j]; C/D: row=quad*4+reg, col=lane&15.
template <int KP, int NP, int LDI, int LDO, int NREAL, int NSTORE>
__device__ __forceinline__ void mfma_layer(
    const unsigned short* __restrict__ Wf, const float* __restrict__ bias,
    const unsigned short* __restrict__ inL, unsigned short* __restrict__ outL,
    int wv, int lane) {
    constexpr int NKT = KP / 32, NCT = NP / 16, CPW = NCT / 8;
    const int quad = lane >> 4, l15 = lane & 15;
    f32x4 acc[2][CPW];
#pragma unroll
    for (int rt = 0; rt < 2; ++rt)
#pragma unroll
        for (int i = 0; i < CPW; ++i) acc[rt][i] = (f32x4){0.f, 0.f, 0.f, 0.f};
    const unsigned short* ap = inL + l15 * LDI + quad * 8;
#pragma unroll
    for (int kt = 0; kt < NKT; ++kt) {
        short8 a0 = *(const short8*)(ap + kt * 32);
        short8 a1 = *(const short8*)(ap + 16 * LDI + kt * 32);
        short8 bf[CPW];
#pragma unroll
        for (int i = 0; i < CPW; ++i)
            bf[i] = *(const short8*)(Wf + ((size_t)((wv + 8 * i) * NKT + kt) * 64 + lane) * 8);
#pragma unroll
        for (int i = 0; i < CPW; ++i) {
            acc[0][i] = __builtin_amdgcn_mfma_f32_16x16x32_bf16(a0, bf[i], acc[0][i], 0, 0, 0);
            acc[1][i] = __builtin_amdgcn_mfma_f32_16x16x32_bf16(a1, bf[i], acc[1][i], 0, 0, 0);
        }
    }
#pragma unroll
    for (int i = 0; i < CPW; ++i) {
        int n = (wv + 8 * i) * 16 + l15;
        if (n < NSTORE) {
            float bv = (n < NREAL) ? bias[n] : 0.f;
#pragma unroll
            for (int rt = 0; rt < 2; ++rt)
#pragma unroll
                for (int r = 0; r < 4; ++r) {
                    int row = rt * 16 + quad * 4 + r;
                    float v = fmaxf(acc[rt][i][r] + bv, 0.f);
                    outL[row * LDO + n] = (n < NREAL) ? f2bf(v) : (unsigned short)0;
                }
        }
    }
}

// ------- fused encoder + expert chain + loss over bucketed rows, 32/block ---
// P (32x392): x bf16 -> delta bf16 (in-place RMW between L1 and L2)
// Q (32x264): h1 -> z -> eh2 ; R (32x328): h2 -> eh1 -> eh3
// 512 threads = 8 waves, column-split 8-way, RT=2 row-tiles per wave.
__global__ __launch_bounds__(512, 4) void fused_kernel(
    const float* __restrict__ x, const float* __restrict__ xn,
    const int* __restrict__ counts, const int* __restrict__ idxlist,
    const unsigned short* __restrict__ Wts,
    const float* __restrict__ b1, const float* __restrict__ b2,
    const float* __restrict__ b3, const float* __restrict__ eb1,
    const float* __restrict__ eb2, const float* __restrict__ eb3,
    const float* __restrict__ eb4, float* __restrict__ out) {
    int e = blockIdx.y;
    int cnt = counts[e];
    int start = blockIdx.x * 32;
    if (start >= cnt) return;
    int nrows = min(32, cnt - start);

    __shared__ unsigned short P[32 * 392];
    __shared__ unsigned short Q[32 * 264];
    __shared__ unsigned short R[32 * 328];
    __shared__ int s_idx[32];
    __shared__ float s_part[8];

    int tid = threadIdx.x;
    int wv = tid >> 6, lane = tid & 63;
    const int quad = lane >> 4, l15 = lane & 15;

    if (tid < 32)
        s_idx[tid] = (tid < nrows) ? idxlist[e * BATCH + start + tid] : -1;
    __syncthreads();

    // stage gathered x rows -> P bf16 ld392 (196 dwords/row), zero pad k>=362
    {
        unsigned* dP = (unsigned*)P;
        for (int i = tid; i < 32 * 196; i += 512) {
            int r = i / 196, c = i - r * 196;
            int b = s_idx[r];
            unsigned pk = 0u;
            if (c < 181 && b >= 0) {
                float2 v = *(const float2*)(x + (size_t)b * 362 + 2 * c);
                pk = (unsigned)f2bf(v.x) | ((unsigned)f2bf(v.y) << 16);
            }
            dP[i] = pk;
        }
    }
    __syncthreads();
    // enc L1: x(Kp384, P ld392) -> h1 (Q ld264)
    mfma_layer<384, 256, 392, 264, 256, 256>(Wts + OFF_W1, b1, P, Q, wv, lane);
    __syncthreads();
    // delta staging: read xn coalesced, delta = xn - x(bf16 in P), overwrite P.
    {
        unsigned* dP = (unsigned*)P;
        for (int i = tid; i < 32 * 196; i += 512) {
            int r = i / 196, c = i - r * 196;
            int b = s_idx[r];
            unsigned pk = 0u;
            if (c < 181 && b >= 0) {
                float2 v = *(const float2*)(xn + (size_t)b * 362 + 2 * c);
                unsigned xp = dP[i];
                float x0 = bf2f(xp & 0xffffu), x1 = bf2f(xp >> 16);
                pk = (unsigned)f2bf(v.x - x0) | ((unsigned)f2bf(v.y - x1) << 16);
            }
            dP[i] = pk;
        }
    }
    // enc L2: h1(Kp256, Q ld264) -> h2 (R ld264 region, 200 real pad 224)
    mfma_layer<256, 256, 264, 264, 200, 224>(Wts + OFF_W2, b2, Q, R, wv, lane);
    __syncthreads();
    // enc L3: h2(Kp224, R ld264) -> z (Q ld136, 100 real sigmoid, pad 128)
    // CPW=1 (Np=128, 8 waves): ct = wv.
    {
        const unsigned short* W3f = Wts + OFF_W3;
        f32x4 acc3[2];
#pragma unroll
        for (int rt = 0; rt < 2; ++rt) acc3[rt] = (f32x4){0.f, 0.f, 0.f, 0.f};
        const unsigned short* ap = R + l15 * 264 + quad * 8;
#pragma unroll
        for (int kt = 0; kt < 7; ++kt) {
            short8 a0 = *(const short8*)(ap + kt * 32);
            short8 a1 = *(const short8*)(ap + 16 * 264 + kt * 32);
            short8 bf = *(const short8*)(W3f + ((size_t)(wv * 7 + kt) * 64 + lane) * 8);
            acc3[0] = __builtin_amdgcn_mfma_f32_16x16x32_bf16(a0, bf, acc3[0], 0, 0, 0);
            acc3[1] = __builtin_amdgcn_mfma_f32_16x16x32_bf16(a1, bf, acc3[1], 0, 0, 0);
        }
        int n = wv * 16 + l15;  // 0..127
        float bv = (n < 100) ? b3[n] : 0.f;
#pragma unroll
        for (int rt = 0; rt < 2; ++rt)
#pragma unroll
            for (int r = 0; r < 4; ++r) {
                int row = rt * 16 + quad * 4 + r;
                float s = 1.0f / (1.0f + expf(-(acc3[rt][r] + bv)));
                Q[row * 136 + n] = (n < 100) ? f2bf(s) : (unsigned short)0;
            }
    }
    __syncthreads();
    // E1: z(Kp128, Q ld136) -> eh1 (R ld168, 150 real pad 160)
    mfma_layer<128, 256, 136, 168, 150, 160>(Wts + OFF_E1 + (size_t)e * 32768,
                                             eb1 + e * 150, Q, R, wv, lane);
    __syncthreads();
    // E2: eh1(Kp160, R ld168) -> eh2 (Q ld264, 250 real pad 256)
    mfma_layer<160, 256, 168, 264, 250, 256>(Wts + OFF_E2 + (size_t)e * 40960,
                                             eb2 + e * 250, R, Q, wv, lane);
    __syncthreads();
    // E3: eh2(Kp256, Q ld264) -> eh3 (R ld328, 300 real pad 320)
    mfma_layer<256, 384, 264, 328, 300, 320>(Wts + OFF_E3 + (size_t)e * 98304,
                                             eb3 + e * 300, Q, R, wv, lane);
    __syncthreads();

    // E4: eh3(Kp320, R ld328), Np=384 (CPW=3), fused loss vs delta (in P)
    float lacc = 0.0f;
    {
        constexpr int NKT = 10, CPW = 3;
        const unsigned short* Wf = Wts + OFF_E4 + (size_t)e * 122880;
        const float* bias4 = eb4 + (size_t)e * 362;
        f32x4 acc[2][CPW];
#pragma unroll
        for (int rt = 0; rt < 2; ++rt)
#pragma unroll
            for (int i = 0; i < CPW; ++i) acc[rt][i] = (f32x4){0.f, 0.f, 0.f, 0.f};
        const unsigned short* ap = R + l15 * 328 + quad * 8;
#pragma unroll
        for (int kt = 0; kt < NKT; ++kt) {
            short8 a0 = *(const short8*)(ap + kt * 32);
            short8 a1 = *(const short8*)(ap + 16 * 328 + kt * 32);
            short8 bf[CPW];
#pragma unroll
            for (int i = 0; i < CPW; ++i)
                bf[i] = *(const short8*)(Wf + ((size_t)((wv + 8 * i) * NKT + kt) * 64 + lane) * 8);
#pragma unroll
            for (int i = 0; i < CPW; ++i) {
                acc[0][i] = __builtin_amdgcn_mfma_f32_16x16x32_bf16(a0, bf[i], acc[0][i], 0, 0, 0);
                acc[1][i] = __builtin_amdgcn_mfma_f32_16x16x32_bf16(a1, bf[i], acc[1][i], 0, 0, 0);
            }
        }
        const float WC0 = 1.0f / 65536.0f;
        const float WCR = 1.0f / (361.0f * 65536.0f);
#pragma unroll
        for (int i = 0; i < CPW; ++i) {
            int n = (wv + 8 * i) * 16 + l15;
            if (n < 362) {
                float bv = bias4[n];
                float wgt = (n == 0) ? WC0 : WCR;
#pragma unroll
                for (int rt = 0; rt < 2; ++rt)
#pragma unroll
                    for (int r = 0; r < 4; ++r) {
                        int row = rt * 16 + quad * 4 + r;
                        int b = s_idx[row];
                        if (b >= 0) {
                            float pred = acc[rt][i][r] + bv;
                            float delta = bf2f((unsigned)P[row * 392 + n]);
                            float err = pred - delta;
                            lacc += wgt * err * err;
                        }
                    }
            }
        }
    }
    // block reduction -> atomicAdd
    for (int off = 32; off; off >>= 1)
        lacc += __shfl_down(lacc, off, 64);
    if ((tid & 63) == 0) s_part[wv] = lacc;
    __syncthreads();
    if (tid == 0) {
        float s = 0.f;
#pragma unroll
        for (int i = 0; i < 8; ++i) s += s_part[i];
        atomicAdd(out, s);
    }
}

extern "C" void kernel_launch(void* const* d_in, const int* in_sizes, int n_in,
                              void* d_out, int out_size, void* d_ws, size_t ws_size,
                              hipStream_t stream) {
    const float* x   = (const float*)d_in[0];
    const float* xn  = (const float*)d_in[1];
    const int*   a   = (const int*)d_in[2];
    const float* W1  = (const float*)d_in[3];
    const float* b1  = (const float*)d_in[4];
    const float* W2  = (const float*)d_in[5];
    const float* b2  = (const float*)d_in[6];
    const float* W3  = (const float*)d_in[7];
    const float* b3  = (const float*)d_in[8];
    const float* eW1 = (const float*)d_in[9];
    const float* eb1 = (const float*)d_in[10];
    const float* eW2 = (const float*)d_in[11];
    const float* eb2 = (const float*)d_in[12];
    const float* eW3 = (const float*)d_in[13];
    const float* eb3 = (const float*)d_in[14];
    const float* eW4 = (const float*)d_in[15];
    const float* eb4 = (const float*)d_in[16];

    char* ws = (char*)d_ws;
    int* counts           = (int*)ws;
    int* idxlist          = (int*)(ws + WS_IDX_OFF);
    unsigned short* Wts   = (unsigned short*)(ws + WS_WT_OFF);

    hipMemsetAsync(counts, 0, 256, stream);
    hipMemsetAsync(d_out, 0, sizeof(float), stream);

    repack_kernel<<<dim3(32, 15), 256, 0, stream>>>(W1, W2, W3, eW1, eW2, eW3, eW4, Wts);
    bucket_kernel<<<BATCH / 256, 256, 0, stream>>>(a, counts, idxlist);
    fused_kernel<<<dim3(BATCH / 32, 3), 512, 0, stream>>>(
        x, xn, counts, idxlist, Wts, b1, b2, b3, eb1, eb2, eb3, eb4, (float*)d_out);
}

// Round 7
// 418.996 us; speedup vs baseline: 1.3061x; 1.0106x over previous
//
#include <hip/hip_runtime.h>
#include <math.h>

// Problem constants
#define BATCH 65536
#define XD 362
#define ZD 100

// ws layout (bytes):
//   [0,256)               : counts[3] (int), zeroed each launch
//   [256, 786688)         : idxlist[3][65536] (int)
//   [786688, +4308992)    : repacked bf16 weights in MFMA B-fragment order
#define WS_IDX_OFF 256
#define WS_WT_OFF  786688

// Weight offsets in bf16 elements. Fragment order: for each matrix,
// index = ((ct*NKT + kt)*64 + lane)*8 + j, where the fragment element is
// B[k = kt*32 + (lane>>4)*8 + j][n = ct*16 + (lane&15)], zero-padded to Kp,Np.
// Np padded to multiples of 128 for the 8-way column split.
#define OFF_W1 0        // Kp=384 Np=256 (98304)
#define OFF_W2 98304    // Kp=256 Np=256 (65536)
#define OFF_W3 163840   // Kp=224 Np=128 (28672)
#define OFF_E1 192512   // 3 x Kp=128 Np=256, stride 32768
#define OFF_E2 290816   // 3 x Kp=160 Np=256, stride 40960
#define OFF_E3 413696   // 3 x Kp=256 Np=384, stride 98304
#define OFF_E4 708608   // 3 x Kp=320 Np=384, stride 122880

typedef short short8 __attribute__((ext_vector_type(8)));
typedef float f32x4 __attribute__((ext_vector_type(4)));

__device__ __forceinline__ unsigned short f2bf(float f) {
    union { float f; unsigned u; } v; v.f = f;
    unsigned u = v.u + 0x7fffu + ((v.u >> 16) & 1u);  // RNE
    return (unsigned short)(u >> 16);
}
__device__ __forceinline__ float bf2f(unsigned u) {
    union { unsigned u; float f; } v; v.u = u << 16; return v.f;
}

// ---------------- repack: W[K][N] fp32 -> bf16 MFMA B-fragment order --------
__global__ __launch_bounds__(256) void repack_kernel(
    const float* __restrict__ W1, const float* __restrict__ W2,
    const float* __restrict__ W3, const float* __restrict__ eW1,
    const float* __restrict__ eW2, const float* __restrict__ eW3,
    const float* __restrict__ eW4, unsigned short* __restrict__ dst) {
    int m = blockIdx.y;
    const float* src; int K, N, Kp, Np; size_t off;
    if (m == 0)      { src = W1; K = 362; N = 256; Kp = 384; Np = 256; off = OFF_W1; }
    else if (m == 1) { src = W2; K = 256; N = 200; Kp = 256; Np = 256; off = OFF_W2; }
    else if (m == 2) { src = W3; K = 200; N = 100; Kp = 224; Np = 128; off = OFF_W3; }
    else if (m <= 5) { int e = m - 3;  src = eW1 + e * 15000;  K = 100; N = 150; Kp = 128; Np = 256; off = OFF_E1 + (size_t)e * 32768; }
    else if (m <= 8) { int e = m - 6;  src = eW2 + e * 37500;  K = 150; N = 250; Kp = 160; Np = 256; off = OFF_E2 + (size_t)e * 40960; }
    else if (m <= 11){ int e = m - 9;  src = eW3 + e * 75000;  K = 250; N = 300; Kp = 256; Np = 384; off = OFF_E3 + (size_t)e * 98304; }
    else             { int e = m - 12; src = eW4 + e * 108600; K = 300; N = 362; Kp = 320; Np = 384; off = OFF_E4 + (size_t)e * 122880; }
    int nkt = Kp / 32;
    int total = Kp * Np;
    for (int i = blockIdx.x * 256 + threadIdx.x; i < total; i += gridDim.x * 256) {
        int j = i & 7, lane = (i >> 3) & 63, t = i >> 9;
        int kt = t % nkt, ct = t / nkt;
        int k = kt * 32 + (lane >> 4) * 8 + j;
        int n = ct * 16 + (lane & 15);
        float v = (k < K && n < N) ? src[(size_t)k * N + n] : 0.0f;
        dst[off + i] = f2bf(v);
    }
}

// ---------------- bucket rows by expert (wave-aggregated atomics) -----------
__global__ __launch_bounds__(256) void bucket_kernel(const int* __restrict__ a,
                                                     int* __restrict__ counts,
                                                     int* __restrict__ idxlist) {
    int b = blockIdx.x * 256 + threadIdx.x;
    int lane = threadIdx.x & 63;
    int e = a[b];
    unsigned long long below = (lane == 63) ? ~0ull >> 1
                                            : ((1ull << (lane + 1)) - 1ull) >> 1;
    int pos = 0;
#pragma unroll
    for (int ee = 0; ee < 3; ++ee) {
        unsigned long long mask = __ballot(e == ee);
        if (e == ee) {
            int leader = __ffsll((long long)mask) - 1;
            int base = 0;
            if (lane == leader)
                base = atomicAdd(&counts[ee], __popcll(mask));
            base = __shfl(base, leader, 64);
            pos = base + __popcll(mask & below);
        }
    }
    idxlist[e * BATCH + pos] = b;
}

// MFMA layer over a 32-row LDS tile, 8-wave column split, RT=2 row-tiles.
// in: bf16 LDS [32][LDI] (zero-padded to KP). out: bf16 LDS [32][LDO],
// relu(acc+bias), cols n<NSTORE written, zeros for NREAL<=n<NSTORE.
// Wave wv owns col-tiles {wv, wv+8, ...}; each B-fragment feeds 2 MFMAs.
// A-frag: [m=lane&15][k=quad*8+j]; C/D: row=quad*4+reg, col=lane&15.
template <int KP, int NP, int LDI, int LDO, int NREAL, int NSTORE>
__device__ __forceinline__ void mfma_layer(
    const unsigned short* __restrict__ Wf, const float* __restrict__ bias,
    const unsigned short* __restrict__ inL, unsigned short* __restrict__ outL,
    int wv, int lane) {
    constexpr int NKT = KP / 32, NCT = NP / 16, CPW = NCT / 8;
    const int quad = lane >> 4, l15 = lane & 15;
    f32x4 acc[2][CPW];
#pragma unroll
    for (int rt = 0; rt < 2; ++rt)
#pragma unroll
        for (int i = 0; i < CPW; ++i) acc[rt][i] = (f32x4){0.f, 0.f, 0.f, 0.f};
    const unsigned short* ap = inL + l15 * LDI + quad * 8;
#pragma unroll
    for (int kt = 0; kt < NKT; ++kt) {
        short8 a0 = *(const short8*)(ap + kt * 32);
        short8 a1 = *(const short8*)(ap + 16 * LDI + kt * 32);
        short8 bf[CPW];
#pragma unroll
        for (int i = 0; i < CPW; ++i)
            bf[i] = *(const short8*)(Wf + ((size_t)((wv + 8 * i) * NKT + kt) * 64 + lane) * 8);
#pragma unroll
        for (int i = 0; i < CPW; ++i) {
            acc[0][i] = __builtin_amdgcn_mfma_f32_16x16x32_bf16(a0, bf[i], acc[0][i], 0, 0, 0);
            acc[1][i] = __builtin_amdgcn_mfma_f32_16x16x32_bf16(a1, bf[i], acc[1][i], 0, 0, 0);
        }
    }
#pragma unroll
    for (int i = 0; i < CPW; ++i) {
        int n = (wv + 8 * i) * 16 + l15;
        if (n < NSTORE) {
            float bv = (n < NREAL) ? bias[n] : 0.f;
#pragma unroll
            for (int rt = 0; rt < 2; ++rt)
#pragma unroll
                for (int r = 0; r < 4; ++r) {
                    int row = rt * 16 + quad * 4 + r;
                    float v = fmaxf(acc[rt][i][r] + bv, 0.f);
                    outL[row * LDO + n] = (n < NREAL) ? f2bf(v) : (unsigned short)0;
                }
        }
    }
}

// ------- fused encoder + expert chain + loss over bucketed rows, 32/block ---
// Two-buffer ping-pong (delta no longer staged in LDS; loss epilogue reads
// x/xn directly — L3-resident, 64B-coalesced per 16-lane group, transient):
//   A (32x392): x -> h2 -> eh1 -> eh3 ;  B (32x264): h1 -> z -> eh2
// 512 threads = 8 waves, column-split 8-way, RT=2 row-tiles per wave.
// LDS ~42 KB -> 3 blocks/CU (24 waves) if VGPR <= 85, hence bounds(512,6).
__global__ __launch_bounds__(512, 6) void fused_kernel(
    const float* __restrict__ x, const float* __restrict__ xn,
    const int* __restrict__ counts, const int* __restrict__ idxlist,
    const unsigned short* __restrict__ Wts,
    const float* __restrict__ b1, const float* __restrict__ b2,
    const float* __restrict__ b3, const float* __restrict__ eb1,
    const float* __restrict__ eb2, const float* __restrict__ eb3,
    const float* __restrict__ eb4, float* __restrict__ out) {
    int e = blockIdx.y;
    int cnt = counts[e];
    int start = blockIdx.x * 32;
    if (start >= cnt) return;
    int nrows = min(32, cnt - start);

    __shared__ unsigned short A[32 * 392];
    __shared__ unsigned short B[32 * 264];
    __shared__ int s_idx[32];
    __shared__ float s_part[8];

    int tid = threadIdx.x;
    int wv = tid >> 6, lane = tid & 63;
    const int quad = lane >> 4, l15 = lane & 15;

    if (tid < 32)
        s_idx[tid] = (tid < nrows) ? idxlist[e * BATCH + start + tid] : -1;
    __syncthreads();

    // stage gathered x rows -> A bf16 ld392 (196 dwords/row), zero pad k>=362
    {
        unsigned* dA = (unsigned*)A;
        for (int i = tid; i < 32 * 196; i += 512) {
            int r = i / 196, c = i - r * 196;
            int b = s_idx[r];
            unsigned pk = 0u;
            if (c < 181 && b >= 0) {
                float2 v = *(const float2*)(x + (size_t)b * 362 + 2 * c);
                pk = (unsigned)f2bf(v.x) | ((unsigned)f2bf(v.y) << 16);
            }
            dA[i] = pk;
        }
    }
    __syncthreads();
    // enc L1: x(Kp384, A ld392) -> h1 (B ld264)
    mfma_layer<384, 256, 392, 264, 256, 256>(Wts + OFF_W1, b1, A, B, wv, lane);
    __syncthreads();
    // enc L2: h1(Kp256, B ld264) -> h2 (A ld264 region, 200 real pad 224)
    mfma_layer<256, 256, 264, 264, 200, 224>(Wts + OFF_W2, b2, B, A, wv, lane);
    __syncthreads();
    // enc L3: h2(Kp224, A ld264) -> z (B ld136, 100 real sigmoid, pad 128)
    // CPW=1 (Np=128, 8 waves): ct = wv.
    {
        const unsigned short* W3f = Wts + OFF_W3;
        f32x4 acc3[2];
#pragma unroll
        for (int rt = 0; rt < 2; ++rt) acc3[rt] = (f32x4){0.f, 0.f, 0.f, 0.f};
        const unsigned short* ap = A + l15 * 264 + quad * 8;
#pragma unroll
        for (int kt = 0; kt < 7; ++kt) {
            short8 a0 = *(const short8*)(ap + kt * 32);
            short8 a1 = *(const short8*)(ap + 16 * 264 + kt * 32);
            short8 bf = *(const short8*)(W3f + ((size_t)(wv * 7 + kt) * 64 + lane) * 8);
            acc3[0] = __builtin_amdgcn_mfma_f32_16x16x32_bf16(a0, bf, acc3[0], 0, 0, 0);
            acc3[1] = __builtin_amdgcn_mfma_f32_16x16x32_bf16(a1, bf, acc3[1], 0, 0, 0);
        }
        int n = wv * 16 + l15;  // 0..127
        float bv = (n < 100) ? b3[n] : 0.f;
#pragma unroll
        for (int rt = 0; rt < 2; ++rt)
#pragma unroll
            for (int r = 0; r < 4; ++r) {
                int row = rt * 16 + quad * 4 + r;
                float s = 1.0f / (1.0f + expf(-(acc3[rt][r] + bv)));
                B[row * 136 + n] = (n < 100) ? f2bf(s) : (unsigned short)0;
            }
    }
    __syncthreads();
    // E1: z(Kp128, B ld136) -> eh1 (A ld168, 150 real pad 160)
    mfma_layer<128, 256, 136, 168, 150, 160>(Wts + OFF_E1 + (size_t)e * 32768,
                                             eb1 + e * 150, B, A, wv, lane);
    __syncthreads();
    // E2: eh1(Kp160, A ld168) -> eh2 (B ld264, 250 real pad 256)
    mfma_layer<160, 256, 168, 264, 250, 256>(Wts + OFF_E2 + (size_t)e * 40960,
                                             eb2 + e * 250, A, B, wv, lane);
    __syncthreads();
    // E3: eh2(Kp256, B ld264) -> eh3 (A ld328, 300 real pad 320)
    mfma_layer<256, 384, 264, 328, 300, 320>(Wts + OFF_E3 + (size_t)e * 98304,
                                             eb3 + e * 300, B, A, wv, lane);
    __syncthreads();

    // E4: eh3(Kp320, A ld328), Np=384 (CPW=3), loss vs (xn-x) read directly
    float lacc = 0.0f;
    {
        constexpr int NKT = 10, CPW = 3;
        const unsigned short* Wf = Wts + OFF_E4 + (size_t)e * 122880;
        const float* bias4 = eb4 + (size_t)e * 362;
        f32x4 acc[2][CPW];
#pragma unroll
        for (int rt = 0; rt < 2; ++rt)
#pragma unroll
            for (int i = 0; i < CPW; ++i) acc[rt][i] = (f32x4){0.f, 0.f, 0.f, 0.f};
        const unsigned short* ap = A + l15 * 328 + quad * 8;
#pragma unroll
        for (int kt = 0; kt < NKT; ++kt) {
            short8 a0 = *(const short8*)(ap + kt * 32);
            short8 a1 = *(const short8*)(ap + 16 * 328 + kt * 32);
            short8 bf[CPW];
#pragma unroll
            for (int i = 0; i < CPW; ++i)
                bf[i] = *(const short8*)(Wf + ((size_t)((wv + 8 * i) * NKT + kt) * 64 + lane) * 8);
#pragma unroll
            for (int i = 0; i < CPW; ++i) {
                acc[0][i] = __builtin_amdgcn_mfma_f32_16x16x32_bf16(a0, bf[i], acc[0][i], 0, 0, 0);
                acc[1][i] = __builtin_amdgcn_mfma_f32_16x16x32_bf16(a1, bf[i], acc[1][i], 0, 0, 0);
            }
        }
        const float WC0 = 1.0f / 65536.0f;
        const float WCR = 1.0f / (361.0f * 65536.0f);
        // loss epilogue: per i-group, scattered-but-64B-coalesced x/xn reads,
        // consumed immediately (transient live range — no cross-MFMA spill).
#pragma unroll
        for (int i = 0; i < CPW; ++i) {
            int n = (wv + 8 * i) * 16 + l15;
            if (n < 362) {
                float bv = bias4[n];
                float wgt = (n == 0) ? WC0 : WCR;
#pragma unroll
                for (int rt = 0; rt < 2; ++rt)
#pragma unroll
                    for (int r = 0; r < 4; ++r) {
                        int row = rt * 16 + quad * 4 + r;
                        int b = s_idx[row];
                        if (b >= 0) {
                            size_t o = (size_t)b * 362 + n;
                            float delta = xn[o] - x[o];
                            float err = acc[rt][i][r] + bv - delta;
                            lacc += wgt * err * err;
                        }
                    }
            }
        }
    }
    // block reduction -> atomicAdd
    for (int off = 32; off; off >>= 1)
        lacc += __shfl_down(lacc, off, 64);
    if ((tid & 63) == 0) s_part[wv] = lacc;
    __syncthreads();
    if (tid == 0) {
        float s = 0.f;
#pragma unroll
        for (int i = 0; i < 8; ++i) s += s_part[i];
        atomicAdd(out, s);
    }
}

extern "C" void kernel_launch(void* const* d_in, const int* in_sizes, int n_in,
                              void* d_out, int out_size, void* d_ws, size_t ws_size,
                              hipStream_t stream) {
    const float* x   = (const float*)d_in[0];
    const float* xn  = (const float*)d_in[1];
    const int*   a   = (const int*)d_in[2];
    const float* W1  = (const float*)d_in[3];
    const float* b1  = (const float*)d_in[4];
    const float* W2  = (const float*)d_in[5];
    const float* b2  = (const float*)d_in[6];
    const float* W3  = (const float*)d_in[7];
    const float* b3  = (const float*)d_in[8];
    const float* eW1 = (const float*)d_in[9];
    const float* eb1 = (const float*)d_in[10];
    const float* eW2 = (const float*)d_in[11];
    const float* eb2 = (const float*)d_in[12];
    const float* eW3 = (const float*)d_in[13];
    const float* eb3 = (const float*)d_in[14];
    const float* eW4 = (const float*)d_in[15];
    const float* eb4 = (const float*)d_in[16];

    char* ws = (char*)d_ws;
    int* counts           = (int*)ws;
    int* idxlist          = (int*)(ws + WS_IDX_OFF);
    unsigned short* Wts   = (unsigned short*)(ws + WS_WT_OFF);

    hipMemsetAsync(counts, 0, 256, stream);
    hipMemsetAsync(d_out, 0, sizeof(float), stream);

    repack_kernel<<<dim3(32, 15), 256, 0, stream>>>(W1, W2, W3, eW1, eW2, eW3, eW4, Wts);
    bucket_kernel<<<BATCH / 256, 256, 0, stream>>>(a, counts, idxlist);
    fused_kernel<<<dim3(BATCH / 32, 3), 512, 0, stream>>>(
        x, xn, counts, idxlist, Wts, b1, b2, b3, eb1, eb2, eb3, eb4, (float*)d_out);
}